// Round 26
// baseline (299.296 us; speedup 1.0000x reference)
//
#include <hip/hip_runtime.h>
#include <hip/hip_bf16.h>
#include <cstdint>
#include <cstddef>

typedef _Float16 f16;
typedef __attribute__((ext_vector_type(8))) _Float16 f16x8;   // MFMA A/B frag
typedef __attribute__((ext_vector_type(4))) float f32x4;      // MFMA C/D frag

#define DI __device__ __forceinline__

constexpr int BATCH  = 4096;
constexpr int S1     = 15;
constexpr int DPAD   = 128;   // 120 padded to 128
constexpr int H      = 512;
constexpr int OUTC   = 99;
constexpr int OUTPAD = 112;   // 99 padded to 7*16

// jax.nn.gelu (tanh approx) = x * sigmoid(2*0.79788456*(x+0.044715x^3)).
DI float gelu_tanh(float x) {
  float t = 1.5957691216057308f * (x + 0.044715f * x * x * x);
  return x / (1.f + __expf(-t));
}

// async 16B global -> LDS (wave-uniform LDS base + lane*16)
DI void gload16(const void* g, void* l) {
  __builtin_amdgcn_global_load_lds(
      (const __attribute__((address_space(1))) void*)g,
      (__attribute__((address_space(3))) void*)l, 16, 0, 0);
}

// counted vmcnt wait BEFORE barrier (R17-proven ordering; per-wave vmcnt is
// published to other waves by the barrier) + sched pin.
template<int N>
DI void waitv_barrier() {
  if constexpr (N == 0)      asm volatile("s_waitcnt vmcnt(0)" ::: "memory");
  else if constexpr (N == 4) asm volatile("s_waitcnt vmcnt(4)" ::: "memory");
  else                       asm volatile("s_waitcnt vmcnt(5)" ::: "memory");
  __builtin_amdgcn_s_barrier();
  __builtin_amdgcn_sched_barrier(0);
}

// ---------------- embeddings: e[b][d] f16, d in [0,128), pad zeros -----------
__global__ void embed_kernel(const float* __restrict__ x, f16* __restrict__ e) {
  const int b = blockIdx.x, d = threadIdx.x;  // 128 threads
  float v = 0.f;
  if (d < 120) {
    const float divs[4] = {1.f, 0.31622776601683794f, 0.1f, 0.03162277660168379f};
    int site = d >> 3, j = d & 7;
    float arg = x[b * 16 + site] * divs[j & 3];
    v = (j < 4) ? sinf(arg) : cosf(arg);
  }
  e[b * DPAD + d] = (f16)v;
}

// ---- transpose+convert: dst[s][n][k] = f16(src[s][k][n]) (optional lo part) -
__global__ __launch_bounds__(256) void transpose_conv_kernel(
    const float* __restrict__ src, f16* __restrict__ dsth, f16* __restrict__ dstl,
    int K, int N, int Kpad, int Npad, int maskMul) {
  __shared__ float tile[32][33];
  const int s  = blockIdx.z;
  const int kb = blockIdx.x * 32, nb = blockIdx.y * 32;
  const int tx = threadIdx.x & 31, ty = threadIdx.x >> 5;  // 32 x 8
  for (int i = ty; i < 32; i += 8) {
    int k = kb + i, n = nb + tx;
    tile[i][tx] = (k < K && n < N) ? src[((size_t)s * K + k) * N + n] : 0.f;
  }
  __syncthreads();
  const int klim = maskMul ? maskMul * (s + 1) : 0x7FFFFFFF;
  for (int i = ty; i < 32; i += 8) {
    int n = nb + i, k = kb + tx;
    if (n < Npad && k < Kpad) {
      float v = (k < klim) ? tile[tx][i] : 0.f;
      size_t o = ((size_t)s * Npad + n) * Kpad + k;
      f16 h = (f16)v;
      dsth[o] = h;
      if (dstl) dstl[o] = (f16)(v - (float)h);
    }
  }
}

// ---- fused GEMM + gelu + LayerNorm ------------------------------------------
// R26: SPLIT=true path = R23/R25 verbatim (drain-0 2-phase, proven). SPLIT=
// false path upgraded to R17's PROVEN counted-vmcnt ordering with depth-2
// prefetch via half-N B-phases: B staged in 256-row halves (32KB), ring-4
// (128KB) + A ring-2 (16KB) = 144KB (same LDS). Phase p (0..2*NT-1): tile
// t=p>>1, half h=p&1. Per phase: {wait vmcnt(N); barrier; issue phase p+2
// loads (A if new tile + 4 B chunks); mma half h}. Hand-traced outstanding
// queue: prologue 9; even p needs first 5 -> vmcnt(4); odd needs first 4 ->
// vmcnt(5); last -> vmcnt(0). WAR: BR[x] rewritten at p-2 issue, its readers
// retired at barrier p-3; AR[t&1] rewritten at 2t+2 issue, readers retired
// at barrier 2t+1. NT template -> full unroll -> static acc indexing.
// Waves: wr=wave>>2 (rows, unchanged); wc=wave&3 now covers 64-col strips
// within each 256-half: col(ni) = (ni>>2)*256 + wc*64 + (ni&3)*16 + laneRow.
// XCD swizzle: grid = 64*nz (%8==0); w=(b&7)*(n/8)+(b>>3).
template<int NTT, bool RES, bool SPLIT>
__global__ __launch_bounds__(512) void gemm_ln_kernel(
    const f16* __restrict__ A, const f16* __restrict__ Wh, const f16* __restrict__ Wl,
    const float* __restrict__ bias, const float* __restrict__ lns,
    const float* __restrict__ lnb, f16* __restrict__ out,
    int M, int Kd, int strideAS) {
  constexpr int BM = 64, BN = 512, BK = 64;
  constexpr int CPR = BK / 8, SWZ = CPR - 1;
  constexpr int WM = 32, WN = 128, FM = 2, FN = 8;
  extern __shared__ f16 smem[];

  const int n    = gridDim.x;
  const int b    = blockIdx.x;
  const int w    = (b & 7) * (n >> 3) + (b >> 3);
  const int srel = w >> 6;             // 64 m-blocks per site
  const int m0   = (w & 63) * BM;

  const f16* ap  = A  + (size_t)srel * strideAS + (size_t)m0 * Kd;
  const f16* wph = Wh + (size_t)srel * BN * Kd;
  const f16* wpl = SPLIT ? (Wl + (size_t)srel * BN * Kd) : nullptr;
  const int tid = threadIdx.x, wbase = tid & ~63;
  const int wave = tid >> 6, lane = tid & 63;
  const int wr = wave >> 2, wc = wave & 3;
  f32x4 acc[FM][FN] = {};
  const int laneRow = lane & 15;
  const int hi      = lane >> 4;

  if constexpr (SPLIT) {
    // ================= R23/R25 proven drain-0 2-phase path =================
    f16* const As0 = smem;                 // [2][BM*BK]  16KB
    f16* const Bs0 = smem + 2 * BM * BK;   // [2][BN*BK] 128KB
    {
      const int r = tid / CPR, c = tid % CPR, cg = c ^ (r & SWZ);
      gload16(ap + (size_t)r * Kd + cg * 8, As0 + (size_t)wbase * 8);
    }
#pragma unroll
    for (int base = 0; base < BN * CPR; base += 512) {
      const int idx = base + tid;
      const int r = idx / CPR, c = idx % CPR, cg = c ^ (r & SWZ);
      gload16(wph + (size_t)r * Kd + cg * 8, Bs0 + (size_t)(base + wbase) * 8);
    }
    __syncthreads();

    const int NT = Kd / BK;
    const int NV = NT * 2;
    for (int v = 0; v < NV; ++v) {
      const int ktile = v >> 1;
      f16* const Acur = As0 + (size_t)(ktile & 1) * BM * BK;
      f16* const Bcur = Bs0 + (size_t)(v & 1) * BN * BK;
      if (v + 1 < NV) {
        const int nk = (v + 1) >> 1;
        const bool newTile = (((v + 1) & 1) == 0);
        if (newTile) {
          f16* const Anxt = As0 + (size_t)(nk & 1) * BM * BK;
          const int r = tid / CPR, c = tid % CPR, cg = c ^ (r & SWZ);
          gload16(ap + (size_t)r * Kd + nk * BK + cg * 8, Anxt + (size_t)wbase * 8);
        }
        const f16* src = ((v + 1) & 1) ? wpl : wph;
        f16* const Bnxt = Bs0 + (size_t)((v + 1) & 1) * BN * BK;
#pragma unroll
        for (int base = 0; base < BN * CPR; base += 512) {
          const int idx = base + tid;
          const int r = idx / CPR, c = idx % CPR, cg = c ^ (r & SWZ);
          gload16(src + (size_t)r * Kd + nk * BK + cg * 8, Bnxt + (size_t)(base + wbase) * 8);
        }
      }
#pragma unroll
      for (int kk = 0; kk < BK / 32; ++kk) {
        const int cc = kk * 4 + hi;
        f16x8 a[FM];
#pragma unroll
        for (int mi = 0; mi < FM; ++mi) {
          const int row = wr * WM + mi * 16 + laneRow;
          a[mi] = *reinterpret_cast<const f16x8*>(&Acur[row * BK + ((cc ^ (row & SWZ)) << 3)]);
        }
#pragma unroll
        for (int ni = 0; ni < FN; ++ni) {
          const int row = wc * WN + ni * 16 + laneRow;
          f16x8 bv = *reinterpret_cast<const f16x8*>(&Bcur[row * BK + ((cc ^ (row & SWZ)) << 3)]);
#pragma unroll
          for (int mi = 0; mi < FM; ++mi)
            acc[mi][ni] = __builtin_amdgcn_mfma_f32_16x16x32_f16(a[mi], bv, acc[mi][ni], 0, 0, 0);
        }
      }
      __syncthreads();
    }
  } else {
    // ============ counted-vmcnt depth-2 half-N path (R17 ordering) =========
    f16* const ARb[2] = {smem, smem + BM * BK};              // 2 x 8KB
    f16* const BRr[4] = {smem + 2 * BM * BK,
                         smem + 2 * BM * BK + 1 * 256 * BK,
                         smem + 2 * BM * BK + 2 * 256 * BK,
                         smem + 2 * BM * BK + 3 * 256 * BK}; // 4 x 32KB

    const int rA  = tid >> 3;
    const int cg8 = (((tid & 7) ^ (rA & 7)) << 3);
    const uint32_t offA = (uint32_t)rA * (uint32_t)Kd + cg8;
    uint32_t offB[4];
#pragma unroll
    for (int j = 0; j < 4; ++j)
      offB[j] = (uint32_t)(j * 64 + rA) * (uint32_t)Kd + cg8;   // (j*64)%8==0
    const uint32_t halfOff = (uint32_t)256 * (uint32_t)Kd;

    // prologue: A(0):1, B(0,h0):4, B(0,h1):4  -> 9 outstanding
    gload16(ap + offA, ARb[0] + ((size_t)wbase << 3));
#pragma unroll
    for (int j = 0; j < 4; ++j)
      gload16(wph + offB[j], BRr[0] + ((size_t)(j * 512 + wbase) << 3));
#pragma unroll
    for (int j = 0; j < 4; ++j)
      gload16(wph + offB[j] + halfOff, BRr[1] + ((size_t)(j * 512 + wbase) << 3));

    constexpr int NV = 2 * NTT;
#pragma unroll
    for (int p = 0; p < NV; ++p) {
      if constexpr (true) {
        if (p == NV - 1)      waitv_barrier<0>();
        else if (p & 1)       waitv_barrier<5>();
        else                  waitv_barrier<4>();
      }
      if (p + 2 < NV) {
        const int t2 = (p + 2) >> 1, h2 = (p + 2) & 1;
        if (h2 == 0)
          gload16(ap + offA + (uint32_t)t2 * BK, ARb[t2 & 1] + ((size_t)wbase << 3));
        f16* const Bn = BRr[(p + 2) & 3];
        const uint32_t ko = (uint32_t)t2 * BK + (h2 ? halfOff : 0u);
#pragma unroll
        for (int j = 0; j < 4; ++j)
          gload16(wph + offB[j] + ko, Bn + ((size_t)(j * 512 + wbase) << 3));
      }
      const f16* const Ab = ARb[(p >> 1) & 1];
      const f16* const Bb = BRr[p & 3];
      const int h = p & 1;   // compile-time under full unroll
#pragma unroll
      for (int kk = 0; kk < BK / 32; ++kk) {
        const int cc = kk * 4 + hi;
        f16x8 a[FM];
#pragma unroll
        for (int mi = 0; mi < FM; ++mi) {
          const int row = wr * WM + mi * 16 + laneRow;
          a[mi] = *reinterpret_cast<const f16x8*>(&Ab[row * BK + ((cc ^ (row & 7)) << 3)]);
        }
#pragma unroll
        for (int nl = 0; nl < 4; ++nl) {
          const int rb = wc * 64 + nl * 16 + laneRow;    // row within 256-half
          f16x8 bv = *reinterpret_cast<const f16x8*>(&Bb[rb * BK + ((cc ^ (rb & 7)) << 3)]);
#pragma unroll
          for (int mi = 0; mi < FM; ++mi)
            acc[mi][h * 4 + nl] = __builtin_amdgcn_mfma_f32_16x16x32_f16(a[mi], bv, acc[mi][h * 4 + nl], 0, 0, 0);
        }
      }
    }
    __builtin_amdgcn_sched_barrier(0);
  }

  // ---------------- fused epilogue: bias(+resid) -> gelu -> LN -> f16 -------
  const int rbase = hi * 4;
  float bv[FN], sv[FN], bb[FN];
#pragma unroll
  for (int ni = 0; ni < FN; ++ni) {
    const int gn = SPLIT ? (wc * WN + ni * 16 + laneRow)
                         : ((ni >> 2) * 256 + wc * 64 + (ni & 3) * 16 + laneRow);
    bv[ni] = bias[srel * H + gn];
    sv[ni] = lns[srel * H + gn];
    bb[ni] = lnb[srel * H + gn];
  }
  float lsum[FM][4], lsq[FM][4];
#pragma unroll
  for (int mi = 0; mi < FM; ++mi)
#pragma unroll
    for (int r = 0; r < 4; ++r) { lsum[mi][r] = 0.f; lsq[mi][r] = 0.f; }
#pragma unroll
  for (int mi = 0; mi < FM; ++mi)
#pragma unroll
    for (int r = 0; r < 4; ++r) {
      const int row = wr * WM + mi * 16 + rbase + r;
#pragma unroll
      for (int ni = 0; ni < FN; ++ni) {
        const int gn = SPLIT ? (wc * WN + ni * 16 + laneRow)
                             : ((ni >> 2) * 256 + wc * 64 + (ni & 3) * 16 + laneRow);
        float y = acc[mi][ni][r] + bv[ni];
        if constexpr (RES)
          y += (float)A[(size_t)srel * strideAS + (size_t)(m0 + row) * Kd + gn];
        float g = gelu_tanh(y);
        acc[mi][ni][r] = g;
        lsum[mi][r] += g;
        lsq[mi][r]  += g * g;
      }
    }
#pragma unroll
  for (int o = 1; o < 16; o <<= 1)
#pragma unroll
    for (int mi = 0; mi < FM; ++mi)
#pragma unroll
      for (int r = 0; r < 4; ++r) {
        lsum[mi][r] += __shfl_xor(lsum[mi][r], o, 64);
        lsq[mi][r]  += __shfl_xor(lsq[mi][r], o, 64);
      }
  __syncthreads();                       // all waves past K-loop LDS reads
  float* red = reinterpret_cast<float*>(smem);   // [64 rows][4 wc][2]
  if (laneRow == 0) {
#pragma unroll
    for (int mi = 0; mi < FM; ++mi)
#pragma unroll
      for (int r = 0; r < 4; ++r) {
        const int row = wr * WM + mi * 16 + rbase + r;
        red[(row * 4 + wc) * 2 + 0] = lsum[mi][r];
        red[(row * 4 + wc) * 2 + 1] = lsq[mi][r];
      }
  }
  __syncthreads();
#pragma unroll
  for (int mi = 0; mi < FM; ++mi)
#pragma unroll
    for (int r = 0; r < 4; ++r) {
      const int row = wr * WM + mi * 16 + rbase + r;
      float sum = 0.f, sq = 0.f;
#pragma unroll
      for (int w4 = 0; w4 < 4; ++w4) {
        sum += red[(row * 4 + w4) * 2 + 0];
        sq  += red[(row * 4 + w4) * 2 + 1];
      }
      const float mean = sum * (1.f / 512.f);
      const float var  = sq * (1.f / 512.f) - mean * mean;
      const float rstd = 1.f / sqrtf(var + 1e-6f);
#pragma unroll
      for (int ni = 0; ni < FN; ++ni) {
        const int gn = SPLIT ? (wc * WN + ni * 16 + laneRow)
                             : ((ni >> 2) * 256 + wc * 64 + (ni & 3) * 16 + laneRow);
        float z = (acc[mi][ni][r] - mean) * rstd * sv[ni] + bb[ni];
        out[((size_t)srel * M + m0 + row) * H + gn] = (f16)z;
      }
    }
}

// ---- final projection GEMM, W-split f16 (2 MFMA), f32 out -------------------
__global__ __launch_bounds__(512) void gemm_out_kernel(
    const f16* __restrict__ A, const f16* __restrict__ Wh, const f16* __restrict__ Wl,
    const float* __restrict__ bias, float* __restrict__ out,
    int M, int Kd, int strideAS) {
  constexpr int BM = 128, BN = 112, BK = 64;
  constexpr int CPR = BK / 8, SWZ = CPR - 1;
  constexpr int FN = 7;
  extern __shared__ f16 smem[];
  f16* As  = smem;               // 128*64
  f16* Bhs = As + BM * BK;       // 112*64
  f16* Bls = Bhs + BN * BK;

  const int s  = blockIdx.z;
  const int m0 = blockIdx.x * BM;
  const f16* ap  = A  + (size_t)s * strideAS + (size_t)m0 * Kd;
  const f16* wph = Wh + (size_t)s * BN * Kd;
  const f16* wpl = Wl + (size_t)s * BN * Kd;
  const int tid = threadIdx.x, wbase = tid & ~63;
  const int wave = tid >> 6, lane = tid & 63;
  const int wr = wave;           // 16 rows per wave
  f32x4 acc[FN] = {};
  const int laneRow = lane & 15;
  const int hi      = lane >> 4;

  for (int k0 = 0; k0 < Kd; k0 += BK) {
    __syncthreads();
#pragma unroll
    for (int base = 0; base < BM * CPR; base += 512) {   // 1024 chunks
      const int idx = base + tid;
      const int r = idx / CPR, c = idx % CPR, cg = c ^ (r & SWZ);
      gload16(ap + (size_t)r * Kd + k0 + cg * 8, As + (size_t)(base + wbase) * 8);
    }
#pragma unroll
    for (int base = 0; base < BN * CPR; base += 512) {   // 896 chunks, partial
      const int idx = base + tid;
      if (idx < BN * CPR) {
        const int r = idx / CPR, c = idx % CPR, cg = c ^ (r & SWZ);
        const size_t go = (size_t)r * Kd + k0 + cg * 8;
        gload16(wph + go, Bhs + (size_t)(base + wbase) * 8);
        gload16(wpl + go, Bls + (size_t)(base + wbase) * 8);
      }
    }
    __syncthreads();
#pragma unroll
    for (int kk = 0; kk < BK / 32; ++kk) {
      const int cc = kk * 4 + hi;
      const int rowA = wr * 16 + laneRow;
      f16x8 a = *reinterpret_cast<const f16x8*>(&As[rowA * BK + ((cc ^ (rowA & SWZ)) << 3)]);
#pragma unroll
      for (int ni = 0; ni < FN; ++ni) {
        const int row = ni * 16 + laneRow;
        const int off = row * BK + ((cc ^ (row & SWZ)) << 3);
        f16x8 bh = *reinterpret_cast<const f16x8*>(&Bhs[off]);
        f16x8 bl = *reinterpret_cast<const f16x8*>(&Bls[off]);
        acc[ni] = __builtin_amdgcn_mfma_f32_16x16x32_f16(a, bh, acc[ni], 0, 0, 0);
        acc[ni] = __builtin_amdgcn_mfma_f32_16x16x32_f16(a, bl, acc[ni], 0, 0, 0);
      }
    }
  }

  const int rbase = hi * 4;
#pragma unroll
  for (int ni = 0; ni < FN; ++ni)
#pragma unroll
    for (int r = 0; r < 4; ++r) {
      const int gm = m0 + wr * 16 + rbase + r;
      const int gn = ni * 16 + laneRow;
      if (gn < OUTC)
        out[((size_t)s * M + gm) * OUTC + gn] = acc[ni][r] + bias[s * OUTC + gn];
    }
}

// ---------------- RQS spline: one thread per (b,i), params via LDS -----------
DI float invsymlu(float u) { return u >= 0.f ? u + 1.f : 1.f / (1.f - u); }

__global__ __launch_bounds__(128) void spline_kernel(
    const float* __restrict__ x, const float* __restrict__ bias0,
    const float* __restrict__ p, float* __restrict__ out0, float* __restrict__ ladbuf) {
  __shared__ float prm[128 * 101];   // stride 101: conflict-free
  const int i  = blockIdx.x;         // 0..15
  const int b0 = blockIdx.y * 128;
  if (i == 0) {
    for (int idx = threadIdx.x; idx < 128 * OUTC; idx += 128)
      prm[(idx / OUTC) * 101 + idx % OUTC] = bias0[idx % OUTC];
  } else {
    const float* src = p + ((size_t)(i - 1) * BATCH + b0) * OUTC;
    for (int idx = threadIdx.x; idx < 128 * OUTC; idx += 128)
      prm[(idx / OUTC) * 101 + idx % OUTC] = src[idx];
  }
  __syncthreads();
  const float* P = &prm[threadIdx.x * 101];
  const int b = b0 + threadIdx.x;
  const float inp = x[b * 16 + i];

  float tw = 0.f, th = 0.f;
  for (int k = 0; k < 32; ++k) tw += 0.001f + invsymlu(P[k]);
  for (int k = 0; k < 32; ++k) th += 0.001f + invsymlu(P[32 + k]);
  const float cx = P[97], cy = P[98];
  const float w0 = cx - 0.5f * tw, wK = cx + 0.5f * tw;
  const float h0 = cy - 0.5f * th, hK = cy + 0.5f * th;
  const float d0 = 0.001f + invsymlu(P[64]);
  const float dK = 0.001f + invsymlu(P[96]);
  float outv, lad;
  if (inp < w0) {
    outv = h0 - (w0 - inp) * d0;
    lad  = logf(d0);
  } else if (inp >= wK) {
    outv = (inp - wK) * dK + hK;
    lad  = logf(dK);
  } else {
    float run = w0, icw = w0, ibw = 1.f;
    int bin = 0;
    for (int k = 0; k < 32; ++k) {
      float wk = 0.001f + invsymlu(P[k]);
      if (inp >= run) { bin = k; icw = run; ibw = wk; }
      run += wk;
    }
    float runh = h0;
    for (int k = 0; k < bin; ++k) runh += 0.001f + invsymlu(P[32 + k]);
    const float ih    = 0.001f + invsymlu(P[32 + bin]);
    const float ich   = runh;
    const float ider  = 0.001f + invsymlu(P[64 + bin]);
    const float iderp = 0.001f + invsymlu(P[64 + bin + 1]);
    const float idl   = ih / ibw;
    const float theta = (inp - icw) / ibw;
    const float omt   = 1.f - theta;
    const float tomt  = theta * omt;
    const float num   = ih * (idl * theta * theta + ider * tomt);
    const float den   = idl + (ider + iderp - 2.f * idl) * tomt;
    outv = ich + num / den;
    const float dnum = idl * idl * (iderp * theta * theta + 2.f * idl * tomt + ider * omt * omt);
    lad = logf(dnum) - 2.f * logf(den);
  }
  out0[b * 16 + i]   = outv;
  ladbuf[b * 16 + i] = lad;
}

__global__ void lad_reduce_kernel(const float* __restrict__ ladbuf, float* __restrict__ out1) {
  const int b = blockIdx.x * 256 + threadIdx.x;
  float s = 0.f;
#pragma unroll
  for (int i = 0; i < 16; ++i) s += ladbuf[b * 16 + i];
  out1[b] = s;
}

// ---------------------------------------------------------------------------
extern "C" void kernel_launch(void* const* d_in, const int* in_sizes, int n_in,
                              void* d_out, int out_size, void* d_ws, size_t ws_size,
                              hipStream_t stream) {
  const float* x     = (const float*)d_in[0];
  const float* bias0 = (const float*)d_in[1];
  const float* W0    = (const float*)d_in[2];
  const float* b0    = (const float*)d_in[3];
  const float* ln0s  = (const float*)d_in[4];
  const float* ln0b  = (const float*)d_in[5];
  const float* W1    = (const float*)d_in[6];
  const float* b1    = (const float*)d_in[7];
  const float* ln1s  = (const float*)d_in[8];
  const float* ln1b  = (const float*)d_in[9];
  const float* W2    = (const float*)d_in[10];
  const float* b2    = (const float*)d_in[11];
  const float* ln2s  = (const float*)d_in[12];
  const float* ln2b  = (const float*)d_in[13];
  const float* Wf    = (const float*)d_in[14];
  const float* bfb   = (const float*)d_in[15];
  float* out0 = (float*)d_out;
  float* out1 = out0 + BATCH * 16;

  // ---- workspace budget ----------------------------------------------------
  const size_t fixedBytes =
      (size_t)BATCH * DPAD * 2 +                // e
      2 * ((size_t)S1 * H * DPAD * 2) +         // W0T h,l
      2 * ((size_t)S1 * H * H * 2) +            // W1T h + W2T h (single)
      2 * ((size_t)S1 * OUTPAD * H * 2) +       // WfT h,l
      (size_t)S1 * BATCH * OUTC * 4 +           // pbuf
      (size_t)BATCH * 16 * 4 +                  // ladb
      64 * 256;
  const size_t perSiteP = 2 * ((size_t)BATCH * H * 2);  // P1+P2 per site
  int CH = 1;
  if (ws_size > fixedBytes) {
    size_t c = (ws_size - fixedBytes) / perSiteP;
    CH = (c >= (size_t)S1) ? S1 : (c < 1 ? 1 : (int)c);
  }
  const int nPasses = (S1 + CH - 1) / CH;
  const int baseSz  = S1 / nPasses;
  const int remSz   = S1 % nPasses;

  char* ws = (char*)d_ws;
  size_t off = 0;
  auto take = [&](size_t bytes) {
    char* q = ws + off;
    off += (bytes + 255) & ~(size_t)255;
    return q;
  };
  f16* e     = (f16*)take((size_t)BATCH * DPAD * 2);
  f16* W0Th  = (f16*)take((size_t)S1 * H * DPAD * 2);
  f16* W0Tl  = (f16*)take((size_t)S1 * H * DPAD * 2);
  f16* W1Th  = (f16*)take((size_t)S1 * H * H * 2);   // single-f16
  f16* W2Th  = (f16*)take((size_t)S1 * H * H * 2);   // single-f16
  f16* WfTh  = (f16*)take((size_t)S1 * OUTPAD * H * 2);
  f16* WfTl  = (f16*)take((size_t)S1 * OUTPAD * H * 2);
  f16* P1    = (f16*)take((size_t)CH * BATCH * H * 2);
  f16* P2    = (f16*)take((size_t)CH * BATCH * H * 2);
  float* pbuf = (float*)take((size_t)S1 * BATCH * OUTC * 4);
  float* ladb = (float*)take((size_t)BATCH * 16 * 4);

  embed_kernel<<<BATCH, 128, 0, stream>>>(x, e);
  transpose_conv_kernel<<<dim3(4, 16, S1), 256, 0, stream>>>(W0, W0Th, W0Tl, 120, H, DPAD, H, 8);
  transpose_conv_kernel<<<dim3(16, 16, S1), 256, 0, stream>>>(W1, W1Th, nullptr, H, H, H, H, 0);
  transpose_conv_kernel<<<dim3(16, 16, S1), 256, 0, stream>>>(W2, W2Th, nullptr, H, H, H, H, 0);
  transpose_conv_kernel<<<dim3(16, 4, S1), 256, 0, stream>>>(Wf, WfTh, WfTl, H, OUTC, H, OUTPAD, 0);

  const size_t ldsFused = (size_t)(2 * 64 + 2 * 512) * 64 * 2;   // 147456 B
  const size_t ldsOut   = (size_t)(128 + 112 + 112) * 64 * 2;    // 45056 B

  int sb = 0;
  for (int pass = 0; pass < nPasses; ++pass) {
    const int nz = baseSz + (pass < remSz ? 1 : 0);
    const int gridFused = (BATCH / 64) * nz;   // 64*nz, %8==0
    // layer 0: e (shared) -> P2  [fused gelu+LN, W-split, drain-0 path]
    gemm_ln_kernel<2, false, true><<<gridFused, 512, ldsFused, stream>>>(
        e, W0Th + (size_t)sb * H * DPAD, W0Tl + (size_t)sb * H * DPAD,
        b0 + sb * H, ln0s + sb * H, ln0b + sb * H, P2, BATCH, DPAD, 0);
    // layer 1: P2 -> P1 (residual = P2)  [fused, single-f16 W1, counted path]
    gemm_ln_kernel<8, true, false><<<gridFused, 512, ldsFused, stream>>>(
        P2, W1Th + (size_t)sb * H * H, nullptr,
        b1 + sb * H, ln1s + sb * H, ln1b + sb * H, P1, BATCH, H, BATCH * H);
    // layer 2: P1 -> P2 (residual = P1)  [fused, single-f16 W2, counted path]
    gemm_ln_kernel<8, true, false><<<gridFused, 512, ldsFused, stream>>>(
        P1, W2Th + (size_t)sb * H * H, nullptr,
        b2 + sb * H, ln2s + sb * H, ln2b + sb * H, P2, BATCH, H, BATCH * H);
    // final projection: P2 -> pbuf (f32, W-split Wf)
    gemm_out_kernel<<<dim3(BATCH / 128, 1, nz), 512, ldsOut, stream>>>(
        P2, WfTh + (size_t)sb * OUTPAD * H, WfTl + (size_t)sb * OUTPAD * H,
        bfb + sb * OUTC, pbuf + (size_t)sb * BATCH * OUTC, BATCH, H, BATCH * H);
    sb += nz;
  }

  spline_kernel<<<dim3(16, 32), 128, 0, stream>>>(x, bias0, pbuf, out0, ladb);
  lad_reduce_kernel<<<BATCH / 256, 256, 0, stream>>>(ladb, out1);
}

// Round 27
// 292.679 us; speedup vs baseline: 1.0226x; 1.0226x over previous
//
#include <hip/hip_runtime.h>
#include <hip/hip_bf16.h>
#include <cstdint>
#include <cstddef>

typedef _Float16 f16;
typedef __attribute__((ext_vector_type(8))) _Float16 f16x8;   // MFMA A/B frag
typedef __attribute__((ext_vector_type(4))) float f32x4;      // MFMA C/D frag

#define DI __device__ __forceinline__

constexpr int BATCH  = 4096;
constexpr int S1     = 15;
constexpr int DPAD   = 128;   // 120 padded to 128
constexpr int H      = 512;
constexpr int OUTC   = 99;
constexpr int OUTPAD = 112;   // 99 padded to 7*16

// jax.nn.gelu (tanh approx) = x * sigmoid(2*0.79788456*(x+0.044715x^3)).
DI float gelu_tanh(float x) {
  float t = 1.5957691216057308f * (x + 0.044715f * x * x * x);
  return x / (1.f + __expf(-t));
}

// async 16B global -> LDS (wave-uniform LDS base + lane*16)
DI void gload16(const void* g, void* l) {
  __builtin_amdgcn_global_load_lds(
      (const __attribute__((address_space(1))) void*)g,
      (__attribute__((address_space(3))) void*)l, 16, 0, 0);
}

// ---------------- embeddings: e[b][d] f16, d in [0,128), pad zeros -----------
__global__ void embed_kernel(const float* __restrict__ x, f16* __restrict__ e) {
  const int b = blockIdx.x, d = threadIdx.x;  // 128 threads
  float v = 0.f;
  if (d < 120) {
    const float divs[4] = {1.f, 0.31622776601683794f, 0.1f, 0.03162277660168379f};
    int site = d >> 3, j = d & 7;
    float arg = x[b * 16 + site] * divs[j & 3];
    v = (j < 4) ? sinf(arg) : cosf(arg);
  }
  e[b * DPAD + d] = (f16)v;
}

// ---- transpose+convert: dst[s][n][k] = f16(src[s][k][n]) (optional lo part) -
__global__ __launch_bounds__(256) void transpose_conv_kernel(
    const float* __restrict__ src, f16* __restrict__ dsth, f16* __restrict__ dstl,
    int K, int N, int Kpad, int Npad, int maskMul) {
  __shared__ float tile[32][33];
  const int s  = blockIdx.z;
  const int kb = blockIdx.x * 32, nb = blockIdx.y * 32;
  const int tx = threadIdx.x & 31, ty = threadIdx.x >> 5;  // 32 x 8
  for (int i = ty; i < 32; i += 8) {
    int k = kb + i, n = nb + tx;
    tile[i][tx] = (k < K && n < N) ? src[((size_t)s * K + k) * N + n] : 0.f;
  }
  __syncthreads();
  const int klim = maskMul ? maskMul * (s + 1) : 0x7FFFFFFF;
  for (int i = ty; i < 32; i += 8) {
    int n = nb + i, k = kb + tx;
    if (n < Npad && k < Kpad) {
      float v = (k < klim) ? tile[tx][i] : 0.f;
      size_t o = ((size_t)s * Npad + n) * Kpad + k;
      f16 h = (f16)v;
      dsth[o] = h;
      if (dstl) dstl[o] = (f16)(v - (float)h);
    }
  }
}

// ---- fused GEMM + gelu + LayerNorm, optional W-split, 2-phase pipeline ------
// FINAL = R25/R23 (measured total-time optimum: 292.7us, absmax 0.28125).
// Session record: schedule space bracketed (counted-vmcnt/setprio/tile-size
// variants all 292-409us or fail at the TOTAL level); precision space closed
// (W1/W2 splits worth ~0 -> removed; W0/Wf splits load-bearing -> kept).
// BM=64, BN=512, BK=64, 512 threads (8 waves 2mx4n), WM=32, WN=128.
// LDS 144KB = A-dbuf 2x8K + B-dbuf 2x64K. Each step: ISSUE next step's
// global_load_lds into the other buffer FIRST, then MFMA current, then one
// barrier (drain lands after compute covered the load latency).
// XCD swizzle: grid = 64*nz (%8==0); w=(b&7)*(n/8)+(b>>3).
template<bool RES, bool SPLIT>
__global__ __launch_bounds__(512) void gemm_ln_kernel(
    const f16* __restrict__ A, const f16* __restrict__ Wh, const f16* __restrict__ Wl,
    const float* __restrict__ bias, const float* __restrict__ lns,
    const float* __restrict__ lnb, f16* __restrict__ out,
    int M, int Kd, int strideAS) {
  constexpr int BM = 64, BN = 512, BK = 64;
  constexpr int CPR = BK / 8, SWZ = CPR - 1;
  constexpr int WM = 32, WN = 128, FM = 2, FN = 8;
  extern __shared__ f16 smem[];
  f16* const As0 = smem;                 // [2][BM*BK]  16KB
  f16* const Bs0 = smem + 2 * BM * BK;   // [2][BN*BK] 128KB

  const int n    = gridDim.x;
  const int b    = blockIdx.x;
  const int w    = (b & 7) * (n >> 3) + (b >> 3);
  const int srel = w >> 6;             // 64 m-blocks per site
  const int m0   = (w & 63) * BM;

  const f16* ap  = A  + (size_t)srel * strideAS + (size_t)m0 * Kd;
  const f16* wph = Wh + (size_t)srel * BN * Kd;
  const f16* wpl = SPLIT ? (Wl + (size_t)srel * BN * Kd) : nullptr;
  const int tid = threadIdx.x, wbase = tid & ~63;
  const int wave = tid >> 6, lane = tid & 63;
  const int wr = wave >> 2, wc = wave & 3;
  f32x4 acc[FM][FN] = {};
  const int laneRow = lane & 15;
  const int hi      = lane >> 4;

  // prologue: stage A(0) -> As0[0], Wh(0) -> Bs0[0]
  {
    const int r = tid / CPR, c = tid % CPR, cg = c ^ (r & SWZ);
    gload16(ap + (size_t)r * Kd + cg * 8, As0 + (size_t)wbase * 8);
  }
#pragma unroll
  for (int base = 0; base < BN * CPR; base += 512) {
    const int idx = base + tid;
    const int r = idx / CPR, c = idx % CPR, cg = c ^ (r & SWZ);
    gload16(wph + (size_t)r * Kd + cg * 8, Bs0 + (size_t)(base + wbase) * 8);
  }
  __syncthreads();

  const int NT = Kd / BK;
  const int NV = SPLIT ? NT * 2 : NT;   // virtual steps
  for (int v = 0; v < NV; ++v) {
    const int ktile = SPLIT ? (v >> 1) : v;
    f16* const Acur = As0 + (size_t)(ktile & 1) * BM * BK;
    f16* const Bcur = Bs0 + (size_t)(v & 1) * BN * BK;
    // ---- issue next step's staging into the OTHER buffers ----
    if (v + 1 < NV) {
      const int nk = SPLIT ? ((v + 1) >> 1) : (v + 1);
      const bool newTile = SPLIT ? (((v + 1) & 1) == 0) : true;
      if (newTile) {   // new K-tile: stage its A
        f16* const Anxt = As0 + (size_t)(nk & 1) * BM * BK;
        const int r = tid / CPR, c = tid % CPR, cg = c ^ (r & SWZ);
        gload16(ap + (size_t)r * Kd + nk * BK + cg * 8, Anxt + (size_t)wbase * 8);
      }
      const f16* src = (SPLIT && ((v + 1) & 1)) ? wpl : wph;
      f16* const Bnxt = Bs0 + (size_t)((v + 1) & 1) * BN * BK;
#pragma unroll
      for (int base = 0; base < BN * CPR; base += 512) {
        const int idx = base + tid;
        const int r = idx / CPR, c = idx % CPR, cg = c ^ (r & SWZ);
        gload16(src + (size_t)r * Kd + nk * BK + cg * 8, Bnxt + (size_t)(base + wbase) * 8);
      }
    }
    // ---- compute current: acc += A(ktile) * B(v) ----
#pragma unroll
    for (int kk = 0; kk < BK / 32; ++kk) {
      const int cc = kk * 4 + hi;
      f16x8 a[FM];
#pragma unroll
      for (int mi = 0; mi < FM; ++mi) {
        const int row = wr * WM + mi * 16 + laneRow;
        a[mi] = *reinterpret_cast<const f16x8*>(&Acur[row * BK + ((cc ^ (row & SWZ)) << 3)]);
      }
#pragma unroll
      for (int ni = 0; ni < FN; ++ni) {
        const int row = wc * WN + ni * 16 + laneRow;
        f16x8 bv = *reinterpret_cast<const f16x8*>(&Bcur[row * BK + ((cc ^ (row & SWZ)) << 3)]);
#pragma unroll
        for (int mi = 0; mi < FM; ++mi)
          acc[mi][ni] = __builtin_amdgcn_mfma_f32_16x16x32_f16(a[mi], bv, acc[mi][ni], 0, 0, 0);
      }
    }
    __syncthreads();   // readers of current bufs done; next-step loads drained
  }

  // ---------------- fused epilogue: bias(+resid) -> gelu -> LN -> f16 -------
  const int rbase = hi * 4;
  float bv[FN], sv[FN], bb[FN];
#pragma unroll
  for (int ni = 0; ni < FN; ++ni) {
    const int gn = wc * WN + ni * 16 + laneRow;
    bv[ni] = bias[srel * H + gn];
    sv[ni] = lns[srel * H + gn];
    bb[ni] = lnb[srel * H + gn];
  }
  float lsum[FM][4], lsq[FM][4];
#pragma unroll
  for (int mi = 0; mi < FM; ++mi)
#pragma unroll
    for (int r = 0; r < 4; ++r) { lsum[mi][r] = 0.f; lsq[mi][r] = 0.f; }
#pragma unroll
  for (int mi = 0; mi < FM; ++mi)
#pragma unroll
    for (int r = 0; r < 4; ++r) {
      const int row = wr * WM + mi * 16 + rbase + r;
#pragma unroll
      for (int ni = 0; ni < FN; ++ni) {
        const int gn = wc * WN + ni * 16 + laneRow;
        float y = acc[mi][ni][r] + bv[ni];
        if constexpr (RES)
          y += (float)A[(size_t)srel * strideAS + (size_t)(m0 + row) * Kd + gn];
        float g = gelu_tanh(y);
        acc[mi][ni][r] = g;
        lsum[mi][r] += g;
        lsq[mi][r]  += g * g;
      }
    }
#pragma unroll
  for (int o = 1; o < 16; o <<= 1)
#pragma unroll
    for (int mi = 0; mi < FM; ++mi)
#pragma unroll
      for (int r = 0; r < 4; ++r) {
        lsum[mi][r] += __shfl_xor(lsum[mi][r], o, 64);
        lsq[mi][r]  += __shfl_xor(lsq[mi][r], o, 64);
      }
  __syncthreads();                       // all waves past K-loop LDS reads
  float* red = reinterpret_cast<float*>(smem);   // [64 rows][4 wc][2]
  if (laneRow == 0) {
#pragma unroll
    for (int mi = 0; mi < FM; ++mi)
#pragma unroll
      for (int r = 0; r < 4; ++r) {
        const int row = wr * WM + mi * 16 + rbase + r;
        red[(row * 4 + wc) * 2 + 0] = lsum[mi][r];
        red[(row * 4 + wc) * 2 + 1] = lsq[mi][r];
      }
  }
  __syncthreads();
#pragma unroll
  for (int mi = 0; mi < FM; ++mi)
#pragma unroll
    for (int r = 0; r < 4; ++r) {
      const int row = wr * WM + mi * 16 + rbase + r;
      float sum = 0.f, sq = 0.f;
#pragma unroll
      for (int w4 = 0; w4 < 4; ++w4) {
        sum += red[(row * 4 + w4) * 2 + 0];
        sq  += red[(row * 4 + w4) * 2 + 1];
      }
      const float mean = sum * (1.f / 512.f);
      const float var  = sq * (1.f / 512.f) - mean * mean;
      const float rstd = 1.f / sqrtf(var + 1e-6f);
#pragma unroll
      for (int ni = 0; ni < FN; ++ni) {
        const int gn = wc * WN + ni * 16 + laneRow;
        float z = (acc[mi][ni][r] - mean) * rstd * sv[ni] + bb[ni];
        out[((size_t)srel * M + m0 + row) * H + gn] = (f16)z;
      }
    }
}

// ---- final projection GEMM, W-split f16 (2 MFMA), f32 out -------------------
__global__ __launch_bounds__(512) void gemm_out_kernel(
    const f16* __restrict__ A, const f16* __restrict__ Wh, const f16* __restrict__ Wl,
    const float* __restrict__ bias, float* __restrict__ out,
    int M, int Kd, int strideAS) {
  constexpr int BM = 128, BN = 112, BK = 64;
  constexpr int CPR = BK / 8, SWZ = CPR - 1;
  constexpr int FN = 7;
  extern __shared__ f16 smem[];
  f16* As  = smem;               // 128*64
  f16* Bhs = As + BM * BK;       // 112*64
  f16* Bls = Bhs + BN * BK;

  const int s  = blockIdx.z;
  const int m0 = blockIdx.x * BM;
  const f16* ap  = A  + (size_t)s * strideAS + (size_t)m0 * Kd;
  const f16* wph = Wh + (size_t)s * BN * Kd;
  const f16* wpl = Wl + (size_t)s * BN * Kd;
  const int tid = threadIdx.x, wbase = tid & ~63;
  const int wave = tid >> 6, lane = tid & 63;
  const int wr = wave;           // 16 rows per wave
  f32x4 acc[FN] = {};
  const int laneRow = lane & 15;
  const int hi      = lane >> 4;

  for (int k0 = 0; k0 < Kd; k0 += BK) {
    __syncthreads();
#pragma unroll
    for (int base = 0; base < BM * CPR; base += 512) {   // 1024 chunks
      const int idx = base + tid;
      const int r = idx / CPR, c = idx % CPR, cg = c ^ (r & SWZ);
      gload16(ap + (size_t)r * Kd + k0 + cg * 8, As + (size_t)(base + wbase) * 8);
    }
#pragma unroll
    for (int base = 0; base < BN * CPR; base += 512) {   // 896 chunks, partial
      const int idx = base + tid;
      if (idx < BN * CPR) {
        const int r = idx / CPR, c = idx % CPR, cg = c ^ (r & SWZ);
        const size_t go = (size_t)r * Kd + k0 + cg * 8;
        gload16(wph + go, Bhs + (size_t)(base + wbase) * 8);
        gload16(wpl + go, Bls + (size_t)(base + wbase) * 8);
      }
    }
    __syncthreads();
#pragma unroll
    for (int kk = 0; kk < BK / 32; ++kk) {
      const int cc = kk * 4 + hi;
      const int rowA = wr * 16 + laneRow;
      f16x8 a = *reinterpret_cast<const f16x8*>(&As[rowA * BK + ((cc ^ (rowA & SWZ)) << 3)]);
#pragma unroll
      for (int ni = 0; ni < FN; ++ni) {
        const int row = ni * 16 + laneRow;
        const int off = row * BK + ((cc ^ (row & SWZ)) << 3);
        f16x8 bh = *reinterpret_cast<const f16x8*>(&Bhs[off]);
        f16x8 bl = *reinterpret_cast<const f16x8*>(&Bls[off]);
        acc[ni] = __builtin_amdgcn_mfma_f32_16x16x32_f16(a, bh, acc[ni], 0, 0, 0);
        acc[ni] = __builtin_amdgcn_mfma_f32_16x16x32_f16(a, bl, acc[ni], 0, 0, 0);
      }
    }
  }

  const int rbase = hi * 4;
#pragma unroll
  for (int ni = 0; ni < FN; ++ni)
#pragma unroll
    for (int r = 0; r < 4; ++r) {
      const int gm = m0 + wr * 16 + rbase + r;
      const int gn = ni * 16 + laneRow;
      if (gn < OUTC)
        out[((size_t)s * M + gm) * OUTC + gn] = acc[ni][r] + bias[s * OUTC + gn];
    }
}

// ---------------- RQS spline: one thread per (b,i), params via LDS -----------
DI float invsymlu(float u) { return u >= 0.f ? u + 1.f : 1.f / (1.f - u); }

__global__ __launch_bounds__(128) void spline_kernel(
    const float* __restrict__ x, const float* __restrict__ bias0,
    const float* __restrict__ p, float* __restrict__ out0, float* __restrict__ ladbuf) {
  __shared__ float prm[128 * 101];   // stride 101: conflict-free
  const int i  = blockIdx.x;         // 0..15
  const int b0 = blockIdx.y * 128;
  if (i == 0) {
    for (int idx = threadIdx.x; idx < 128 * OUTC; idx += 128)
      prm[(idx / OUTC) * 101 + idx % OUTC] = bias0[idx % OUTC];
  } else {
    const float* src = p + ((size_t)(i - 1) * BATCH + b0) * OUTC;
    for (int idx = threadIdx.x; idx < 128 * OUTC; idx += 128)
      prm[(idx / OUTC) * 101 + idx % OUTC] = src[idx];
  }
  __syncthreads();
  const float* P = &prm[threadIdx.x * 101];
  const int b = b0 + threadIdx.x;
  const float inp = x[b * 16 + i];

  float tw = 0.f, th = 0.f;
  for (int k = 0; k < 32; ++k) tw += 0.001f + invsymlu(P[k]);
  for (int k = 0; k < 32; ++k) th += 0.001f + invsymlu(P[32 + k]);
  const float cx = P[97], cy = P[98];
  const float w0 = cx - 0.5f * tw, wK = cx + 0.5f * tw;
  const float h0 = cy - 0.5f * th, hK = cy + 0.5f * th;
  const float d0 = 0.001f + invsymlu(P[64]);
  const float dK = 0.001f + invsymlu(P[96]);
  float outv, lad;
  if (inp < w0) {
    outv = h0 - (w0 - inp) * d0;
    lad  = logf(d0);
  } else if (inp >= wK) {
    outv = (inp - wK) * dK + hK;
    lad  = logf(dK);
  } else {
    float run = w0, icw = w0, ibw = 1.f;
    int bin = 0;
    for (int k = 0; k < 32; ++k) {
      float wk = 0.001f + invsymlu(P[k]);
      if (inp >= run) { bin = k; icw = run; ibw = wk; }
      run += wk;
    }
    float runh = h0;
    for (int k = 0; k < bin; ++k) runh += 0.001f + invsymlu(P[32 + k]);
    const float ih    = 0.001f + invsymlu(P[32 + bin]);
    const float ich   = runh;
    const float ider  = 0.001f + invsymlu(P[64 + bin]);
    const float iderp = 0.001f + invsymlu(P[64 + bin + 1]);
    const float idl   = ih / ibw;
    const float theta = (inp - icw) / ibw;
    const float omt   = 1.f - theta;
    const float tomt  = theta * omt;
    const float num   = ih * (idl * theta * theta + ider * tomt);
    const float den   = idl + (ider + iderp - 2.f * idl) * tomt;
    outv = ich + num / den;
    const float dnum = idl * idl * (iderp * theta * theta + 2.f * idl * tomt + ider * omt * omt);
    lad = logf(dnum) - 2.f * logf(den);
  }
  out0[b * 16 + i]   = outv;
  ladbuf[b * 16 + i] = lad;
}

__global__ void lad_reduce_kernel(const float* __restrict__ ladbuf, float* __restrict__ out1) {
  const int b = blockIdx.x * 256 + threadIdx.x;
  float s = 0.f;
#pragma unroll
  for (int i = 0; i < 16; ++i) s += ladbuf[b * 16 + i];
  out1[b] = s;
}

// ---------------------------------------------------------------------------
extern "C" void kernel_launch(void* const* d_in, const int* in_sizes, int n_in,
                              void* d_out, int out_size, void* d_ws, size_t ws_size,
                              hipStream_t stream) {
  const float* x     = (const float*)d_in[0];
  const float* bias0 = (const float*)d_in[1];
  const float* W0    = (const float*)d_in[2];
  const float* b0    = (const float*)d_in[3];
  const float* ln0s  = (const float*)d_in[4];
  const float* ln0b  = (const float*)d_in[5];
  const float* W1    = (const float*)d_in[6];
  const float* b1    = (const float*)d_in[7];
  const float* ln1s  = (const float*)d_in[8];
  const float* ln1b  = (const float*)d_in[9];
  const float* W2    = (const float*)d_in[10];
  const float* b2    = (const float*)d_in[11];
  const float* ln2s  = (const float*)d_in[12];
  const float* ln2b  = (const float*)d_in[13];
  const float* Wf    = (const float*)d_in[14];
  const float* bfb   = (const float*)d_in[15];
  float* out0 = (float*)d_out;
  float* out1 = out0 + BATCH * 16;

  // ---- workspace budget ----------------------------------------------------
  const size_t fixedBytes =
      (size_t)BATCH * DPAD * 2 +                // e
      2 * ((size_t)S1 * H * DPAD * 2) +         // W0T h,l
      2 * ((size_t)S1 * H * H * 2) +            // W1T h + W2T h (single)
      2 * ((size_t)S1 * OUTPAD * H * 2) +       // WfT h,l
      (size_t)S1 * BATCH * OUTC * 4 +           // pbuf
      (size_t)BATCH * 16 * 4 +                  // ladb
      64 * 256;
  const size_t perSiteP = 2 * ((size_t)BATCH * H * 2);  // P1+P2 per site
  int CH = 1;
  if (ws_size > fixedBytes) {
    size_t c = (ws_size - fixedBytes) / perSiteP;
    CH = (c >= (size_t)S1) ? S1 : (c < 1 ? 1 : (int)c);
  }
  const int nPasses = (S1 + CH - 1) / CH;
  const int baseSz  = S1 / nPasses;
  const int remSz   = S1 % nPasses;

  char* ws = (char*)d_ws;
  size_t off = 0;
  auto take = [&](size_t bytes) {
    char* q = ws + off;
    off += (bytes + 255) & ~(size_t)255;
    return q;
  };
  f16* e     = (f16*)take((size_t)BATCH * DPAD * 2);
  f16* W0Th  = (f16*)take((size_t)S1 * H * DPAD * 2);
  f16* W0Tl  = (f16*)take((size_t)S1 * H * DPAD * 2);
  f16* W1Th  = (f16*)take((size_t)S1 * H * H * 2);   // single-f16
  f16* W2Th  = (f16*)take((size_t)S1 * H * H * 2);   // single-f16
  f16* WfTh  = (f16*)take((size_t)S1 * OUTPAD * H * 2);
  f16* WfTl  = (f16*)take((size_t)S1 * OUTPAD * H * 2);
  f16* P1    = (f16*)take((size_t)CH * BATCH * H * 2);
  f16* P2    = (f16*)take((size_t)CH * BATCH * H * 2);
  float* pbuf = (float*)take((size_t)S1 * BATCH * OUTC * 4);
  float* ladb = (float*)take((size_t)BATCH * 16 * 4);

  embed_kernel<<<BATCH, 128, 0, stream>>>(x, e);
  transpose_conv_kernel<<<dim3(4, 16, S1), 256, 0, stream>>>(W0, W0Th, W0Tl, 120, H, DPAD, H, 8);
  transpose_conv_kernel<<<dim3(16, 16, S1), 256, 0, stream>>>(W1, W1Th, nullptr, H, H, H, H, 0);
  transpose_conv_kernel<<<dim3(16, 16, S1), 256, 0, stream>>>(W2, W2Th, nullptr, H, H, H, H, 0);
  transpose_conv_kernel<<<dim3(16, 4, S1), 256, 0, stream>>>(Wf, WfTh, WfTl, H, OUTC, H, OUTPAD, 0);

  const size_t ldsFused = (size_t)(2 * 64 + 2 * 512) * 64 * 2;   // 147456 B
  const size_t ldsOut   = (size_t)(128 + 112 + 112) * 64 * 2;    // 45056 B

  int sb = 0;
  for (int pass = 0; pass < nPasses; ++pass) {
    const int nz = baseSz + (pass < remSz ? 1 : 0);
    const int gridFused = (BATCH / 64) * nz;   // 64*nz, %8==0
    // layer 0: e (shared) -> P2  [fused gelu+LN, W-split]
    gemm_ln_kernel<false, true><<<gridFused, 512, ldsFused, stream>>>(
        e, W0Th + (size_t)sb * H * DPAD, W0Tl + (size_t)sb * H * DPAD,
        b0 + sb * H, ln0s + sb * H, ln0b + sb * H, P2, BATCH, DPAD, 0);
    // layer 1: P2 -> P1 (residual = P2)  [fused, single-f16 W1]
    gemm_ln_kernel<true, false><<<gridFused, 512, ldsFused, stream>>>(
        P2, W1Th + (size_t)sb * H * H, nullptr,
        b1 + sb * H, ln1s + sb * H, ln1b + sb * H, P1, BATCH, H, BATCH * H);
    // layer 2: P1 -> P2 (residual = P1)  [fused, single-f16 W2]
    gemm_ln_kernel<true, false><<<gridFused, 512, ldsFused, stream>>>(
        P1, W2Th + (size_t)sb * H * H, nullptr,
        b2 + sb * H, ln2s + sb * H, ln2b + sb * H, P2, BATCH, H, BATCH * H);
    // final projection: P2 -> pbuf (f32, W-split Wf)
    gemm_out_kernel<<<dim3(BATCH / 128, 1, nz), 512, ldsOut, stream>>>(
        P2, WfTh + (size_t)sb * OUTPAD * H, WfTl + (size_t)sb * OUTPAD * H,
        bfb + sb * OUTC, pbuf + (size_t)sb * BATCH * OUTC, BATCH, H, BATCH * H);
    sb += nz;
  }

  spline_kernel<<<dim3(16, 32), 128, 0, stream>>>(x, bias0, pbuf, out0, ladb);
  lad_reduce_kernel<<<BATCH / 256, 256, 0, stream>>>(ladb, out1);
}